// Round 4
// baseline (115.898 us; speedup 1.0000x reference)
//
#include <hip/hip_runtime.h>
#include <hip/hip_bf16.h>

typedef __bf16 bf16x8 __attribute__((ext_vector_type(8)));
typedef float floatx4 __attribute__((ext_vector_type(4)));

#define BATCH 256
#define INDIM 512
#define ODIM 10
#define HTOT 18432
#define NMODEL 128
#define HTILE 64
#define BTILE 64
#define BK 32
#define ACT_CHUNK 4608
#define WCNT (HTOT * INDIM)            // 9437184 bf16 elems of w
#define XCNT (BATCH * INDIM)           // 131072 bf16 elems of x
#define NJPG (HTOT / 32)               // 576 aligned 32-neuron groups

// async global->LDS, 16B per lane, dest = wave-uniform base + lane*16
#define GLOAD_LDS(gp, lp) __builtin_amdgcn_global_load_lds( \
    (const __attribute__((address_space(1))) unsigned int*)(const void*)(gp), \
    (__attribute__((address_space(3))) unsigned int*)(lp), 16, 0, 0)

__device__ __forceinline__ unsigned pk2(float a, float b) {
    unsigned ua = __float_as_uint(a);
    ua = (ua + 0x7fffu + ((ua >> 16) & 1u)) >> 16;
    unsigned ub = __float_as_uint(b);
    ub = (ub + 0x7fffu + ((ub >> 16) & 1u)) >> 16;
    return ua | (ub << 16);
}

__device__ __forceinline__ float apply_act(float h, int aidx) {
    if (aidx == 0) return fmaxf(h, 0.f);
    if (aidx == 1) return 1.f - 2.f / (1.f + __expf(2.f * h));   // tanh, no-overflow form
    if (aidx == 2) return 1.f / (1.f + __expf(-h));              // sigmoid
    return h;                                                     // identity
}

// fp32 -> bf16 (RNE) for hidden_w then x, 8 elems/thread, fully streaming.
// grid = (WCNT+XCNT)/8/256 = 4672; blocks 0..4607 are w (exact), rest x.
__global__ __launch_bounds__(256) void convert_kernel(
    const float* __restrict__ hw, const float* __restrict__ x,
    unsigned short* __restrict__ dst)
{
    size_t i = (size_t)(blockIdx.x * 256 + threadIdx.x) * 8;
    const float* src = (i < (size_t)WCNT) ? hw + i : x + (i - WCNT);
    floatx4 v0 = *(const floatx4*)src;
    floatx4 v1 = *(const floatx4*)(src + 4);
    uint4 o;
    o.x = pk2(v0[0], v0[1]); o.y = pk2(v0[2], v0[3]);
    o.z = pk2(v1[0], v1[1]); o.w = pk2(v1[2], v1[3]);
    *(uint4*)(dst + i) = o;
}

// grid = 288 j-blocks * 4 b-blocks = 1152 blocks, 256 threads, 5 blocks/CU.
// 64j x 64b tile, BK=32, global_load_lds(16B) staging, unpadded 64B LDS rows.
// Each wave: 64j x 16b via acc[4] (16x16x32 bf16 MFMA).
__global__ __launch_bounds__(256, 5) void mlp_kernel(
    const unsigned short* __restrict__ wbf, const unsigned short* __restrict__ xbf,
    const float* __restrict__ hidden_b, const float* __restrict__ out_w,
    float* __restrict__ part)
{
    __shared__ __align__(16) unsigned short xs[BTILE * BK];    // 4 KB
    __shared__ __align__(16) unsigned short wsx[HTILE * BK];   // 4 KB
    __shared__ float wtile[ODIM * HTILE];                      // 2.5 KB, [o][64]
    __shared__ float btile[HTILE];

    const int tid = threadIdx.x;
    const int bid = blockIdx.x;
    const int jb = bid >> 2, bb = bid & 3;   // consecutive bids share the w-tile
    const int j0 = jb * HTILE;
    const int b0 = bb * BTILE;
    const int lane = tid & 63;
    const int wvid = tid >> 6;
    const int r = lane & 15;
    const int g = lane >> 4;

    // epilogue-only tiles (first __syncthreads covers them)
    for (int i = tid; i < ODIM * HTILE; i += 256)
        wtile[i] = out_w[(i >> 6) * HTOT + j0 + (i & 63)];
    if (tid < HTILE) btile[tid] = hidden_b[j0 + tid];

    floatx4 acc[4];
    #pragma unroll
    for (int jt = 0; jt < 4; jt++) acc[jt] = (floatx4)0.f;

    // staging: wave wvid owns rows [16*wvid, 16*wvid+16) of each tile;
    // lane L -> row 16*wvid + L/4, k-chunk (L&3)*8  (matches lane*16 LDS dest)
    const int srow = wvid * 16 + (lane >> 2);
    const int scol = (lane & 3) * 8;
    const unsigned short* gw = wbf + (size_t)(j0 + srow) * INDIM + scol;
    const unsigned short* gx = xbf + (size_t)(b0 + srow) * INDIM + scol;
    unsigned short* lw = &wsx[wvid * 16 * BK];   // wave-uniform
    unsigned short* lx = &xs[wvid * 16 * BK];

    for (int kk = 0; kk < INDIM; kk += BK) {
        GLOAD_LDS(gw + kk, lw);
        GLOAD_LDS(gx + kk, lx);
        __syncthreads();
        bf16x8 bfr = *(const bf16x8*)&xs[(wvid * 16 + r) * BK + g * 8];
        #pragma unroll
        for (int jt = 0; jt < 4; jt++) {
            bf16x8 af = *(const bf16x8*)&wsx[(jt * 16 + r) * BK + g * 8];
            acc[jt] = __builtin_amdgcn_mfma_f32_16x16x32_bf16(af, bfr, acc[jt], 0, 0, 0);
        }
        __syncthreads();
    }

    // Epilogue. D layout: col(b) = lane&15, row(j within 16-tile) = (lane>>4)*4 + reg.
    const int aidx = j0 / ACT_CHUNK;             // uniform per block (4608 % 64 == 0)
    const int b = b0 + wvid * 16 + r;

    #pragma unroll
    for (int jp = 0; jp < 2; jp++) {
        const int jpg = (j0 >> 5) + jp;          // global 32-group index
        float a[2][4];
        #pragma unroll
        for (int h = 0; h < 2; h++) {
            int jt = jp * 2 + h;
            #pragma unroll
            for (int q = 0; q < 4; q++)
                a[h][q] = apply_act(acc[jt][q] + btile[jt * 16 + g * 4 + q], aidx);
        }
        #pragma unroll
        for (int o = 0; o < ODIM; o++) {
            float p = 0.f;
            #pragma unroll
            for (int h = 0; h < 2; h++) {
                int jt = jp * 2 + h;
                const float* wr = &wtile[o * HTILE + jt * 16 + g * 4];
                p += a[h][0] * wr[0] + a[h][1] * wr[1] + a[h][2] * wr[2] + a[h][3] * wr[3];
            }
            p += __shfl_xor(p, 16, 64);
            p += __shfl_xor(p, 32, 64);
            if (lane < 16)
                part[((size_t)jpg * ODIM + o) * BATCH + b] = p;   // plain store, one owner
        }
    }
}

// One block per (model, o): 1280 blocks x 256 threads (thread = b).
// Sums the model's 1..8 group partials + out_b, writes out[b][m][o] once.
__global__ __launch_bounds__(256) void finalize_kernel(
    const float* __restrict__ part, const float* __restrict__ out_b,
    float* __restrict__ out)
{
    const int mo = blockIdx.x;           // m*ODIM + o
    const int m = mo / ODIM, o = mo - m * ODIM;
    const int b = threadIdx.x;
    // model m -> rep = m/8, idx = m%8, size = 32*(idx+1)
    const int rep = m >> 3, idx = m & 7;
    const int jp0 = rep * 36 + (idx * (idx + 1)) / 2;
    const int cnt = idx + 1;

    float s = out_b[mo];
    for (int c = 0; c < cnt; c++)
        s += part[((size_t)(jp0 + c) * ODIM + o) * BATCH + b];
    out[((size_t)b * NMODEL + m) * ODIM + o] = s;
}

extern "C" void kernel_launch(void* const* d_in, const int* in_sizes, int n_in,
                              void* d_out, int out_size, void* d_ws, size_t ws_size,
                              hipStream_t stream) {
    const float* x   = (const float*)d_in[0];
    const float* hw  = (const float*)d_in[1];
    const float* hb  = (const float*)d_in[2];
    const float* ow  = (const float*)d_in[3];
    const float* ob  = (const float*)d_in[4];
    float* out = (float*)d_out;

    unsigned short* wbf = (unsigned short*)d_ws;          // 18.9 MB
    unsigned short* xbf = wbf + WCNT;                     // 256 KB
    float* part = (float*)d_ws + (WCNT + XCNT) / 2;       // 5.9 MB, 16B-aligned

    convert_kernel<<<(WCNT + XCNT) / 8 / 256, 256, 0, stream>>>(hw, x, wbf);
    mlp_kernel<<<(HTOT / HTILE) * (BATCH / BTILE), 256, 0, stream>>>(wbf, xbf, hb, ow, part);
    finalize_kernel<<<NMODEL * ODIM, 256, 0, stream>>>(part, ob, out);
}